// Round 1
// baseline (681.479 us; speedup 1.0000x reference)
//
#include <hip/hip_runtime.h>

// Cosine similarity: support_set [S,B,D] f32, X_hat [B,D] f32 -> sim [S,B] f32
//   sim[s,b] = dot(support[s,b,:], X[b,:]) / (max(|support row|,eps)*max(|X row|,eps))
//   normalize: sim = (sim+1)*0.5
// S=512, B=4096, D=64. Memory-bound: 512 MiB support stream dominates.

#define EPS_F 1e-10f

static constexpr int kB = 4096;   // batch (power of 2)
static constexpr int kD = 64;     // feature dim
static constexpr int kS = 512;

// 16 lanes cooperate on one row (16 lanes x float4 = 64 floats = 256 B).
// A 64-lane wave covers 4 consecutive rows -> each global_load_dwordx4 is a
// fully coalesced contiguous 1 KiB across the wave.
__global__ __launch_bounds__(256) void cosine_sim_kernel(
    const float* __restrict__ support,   // [S*B, D] flattened rows
    const float* __restrict__ xhat,      // [B, D]
    const int* __restrict__ normalize_p, // scalar on device
    float* __restrict__ out,             // [S*B]
    int total_rows)
{
    const int norm_flag = *normalize_p;           // uniform, L2-cached
    const int tid       = blockIdx.x * blockDim.x + threadIdx.x;
    const int lane_q    = threadIdx.x & 15;       // quarter-row slot within 16-lane group
    const int row0      = tid >> 4;
    const int row_step  = (gridDim.x * blockDim.x) >> 4;

    for (int row = row0; row < total_rows; row += row_step) {
        const int b = row & (kB - 1);             // row % B (B = 4096, pow2)

        const float4 sv = *reinterpret_cast<const float4*>(
            support + (size_t)row * kD + (size_t)lane_q * 4);
        const float4 xv = *reinterpret_cast<const float4*>(
            xhat + (size_t)b * kD + (size_t)lane_q * 4);

        float dot = sv.x * xv.x + sv.y * xv.y + sv.z * xv.z + sv.w * xv.w;
        float sn  = sv.x * sv.x + sv.y * sv.y + sv.z * sv.z + sv.w * sv.w;
        float xn  = xv.x * xv.x + xv.y * xv.y + xv.z * xv.z + xv.w * xv.w;

        // Reduce across the 16-lane group (xor masks < 16 stay in-group).
        #pragma unroll
        for (int m = 1; m < 16; m <<= 1) {
            dot += __shfl_xor(dot, m, 64);
            sn  += __shfl_xor(sn,  m, 64);
            xn  += __shfl_xor(xn,  m, 64);
        }

        if (lane_q == 0) {
            const float denom = fmaxf(sqrtf(sn), EPS_F) * fmaxf(sqrtf(xn), EPS_F);
            float sim = dot / denom;
            if (norm_flag) sim = (sim + 1.0f) * 0.5f;
            out[row] = sim;
        }
    }
}

extern "C" void kernel_launch(void* const* d_in, const int* in_sizes, int n_in,
                              void* d_out, int out_size, void* d_ws, size_t ws_size,
                              hipStream_t stream) {
    const float* support  = (const float*)d_in[0];   // [S,B,D]
    const float* xhat     = (const float*)d_in[1];   // [B,D]
    const int*   norm_ptr = (const int*)d_in[2];     // scalar
    float*       out      = (float*)d_out;           // [S,B]

    const int total_rows = kS * kB;                  // 2,097,152

    // 2048 blocks x 256 threads = 8 blocks/CU on 256 CUs; grid-stride the rest.
    const int block = 256;
    const int grid  = 2048;
    cosine_sim_kernel<<<grid, block, 0, stream>>>(support, xhat, norm_ptr, out,
                                                  total_rows);
}